// Round 1
// baseline (863.040 us; speedup 1.0000x reference)
//
#include <hip/hip_runtime.h>
#include <hip/hip_bf16.h>
#include <stdint.h>

// TreeLSTM on MI355X. H=D=128, 5H=640, N_LEAVES=2^18, 18 internal levels.
// Strategy: bf16 MFMA (16x16x32) with fp32 accum, fused cell epilogue.
// Weights pre-packed into MFMA B-frag layout; A read直接 from row-major bf16.

#define H5 640
#define HH 128
#define NLEAF 262144

typedef __attribute__((ext_vector_type(4))) float f32x4;
typedef __attribute__((ext_vector_type(8))) short bf16x8;
typedef __attribute__((ext_vector_type(4))) unsigned int u32x4;

static __device__ __forceinline__ unsigned short f2bf(float f) {
  union { float f; unsigned int i; } v; v.f = f;
  unsigned int r = v.i + 0x7FFF + ((v.i >> 16) & 1);  // RNE
  return (unsigned short)(r >> 16);
}

static __device__ __forceinline__ float sigf(float x) {
  return 1.0f / (1.0f + __expf(-x));
}
static __device__ __forceinline__ float tanh_fast(float x) {
  float t = __expf(2.0f * x);        // gates/c bounded (|x| < ~4) -> no overflow
  return (t - 1.0f) / (t + 1.0f);
}

// ---------------------------------------------------------------------------
// Pack a [K,640] f32 weight (rows k<split from srcA, else srcB) into MFMA
// B-fragment layout: frag (nf, kf): lane l holds B[kf*32+(l>>4)*8+e][nf*16+(l&15)],
// e=0..7 contiguous. Element offset = ((nf*KT + kf)*64 + lane)*8.
__global__ void pack_weights(const float* __restrict__ srcA,
                             const float* __restrict__ srcB,
                             int split, int KT, unsigned short* __restrict__ dst) {
  int t = blockIdx.x * blockDim.x + threadIdx.x;
  int total = 40 * KT * 64;
  if (t >= total) return;
  int lane = t & 63;
  int kf = (t >> 6) % KT;
  int nf = (t >> 6) / KT;
  int col = nf * 16 + (lane & 15);
  int k0 = kf * 32 + (lane >> 4) * 8;
  unsigned int w[4];
#pragma unroll
  for (int p = 0; p < 4; ++p) {
    int ka = k0 + 2 * p, kb = k0 + 2 * p + 1;
    float fa = (ka < split) ? srcA[(size_t)ka * H5 + col] : srcB[(size_t)(ka - split) * H5 + col];
    float fb = (kb < split) ? srcA[(size_t)kb * H5 + col] : srcB[(size_t)(kb - split) * H5 + col];
    w[p] = (unsigned int)f2bf(fa) | ((unsigned int)f2bf(fb) << 16);
  }
  u32x4* out = (u32x4*)(dst + (size_t)t * 8);
  u32x4 v; unsigned int* vp = (unsigned int*)&v;
  vp[0] = w[0]; vp[1] = w[1]; vp[2] = w[2]; vp[3] = w[3];
  *out = v;
}

// f32 -> bf16 row-major cast, 8 elements/thread.
__global__ void cast_leaf(const float* __restrict__ src,
                          unsigned short* __restrict__ dst, long n8) {
  long t = (long)blockIdx.x * blockDim.x + threadIdx.x;
  if (t >= n8) return;
  const float4* s = (const float4*)src + t * 2;
  float4 x = s[0], y = s[1];
  u32x4 v; unsigned int* vp = (unsigned int*)&v;
  vp[0] = (unsigned int)f2bf(x.x) | ((unsigned int)f2bf(x.y) << 16);
  vp[1] = (unsigned int)f2bf(x.z) | ((unsigned int)f2bf(x.w) << 16);
  vp[2] = (unsigned int)f2bf(y.x) | ((unsigned int)f2bf(y.y) << 16);
  vp[3] = (unsigned int)f2bf(y.z) | ((unsigned int)f2bf(y.w) << 16);
  *((u32x4*)(dst + t * 8)) = v;
}

// ---------------------------------------------------------------------------
// Fused level kernel: gates = A @ B + b_x, then TreeLSTM cell.
//   A: [n][K] bf16 row-major (K = KT*32; leaf K=128, internal K=256 = h pairs)
//   Bpk: packed weight frags. c_child: [2n][128] f32 (internal only).
// Block: 256 threads = 4 waves, tile 64 rows x 64 h-cols (= 5x64 gate cols).
// Wave: 32 rows x 32 h-cols -> 2 M-frags x (5 gates x 2 N-frags) = 20 MFMAs/K-step.
template <int KT, bool LEAF>
__global__ __launch_bounds__(256, 2) void level_fused(
    const unsigned short* __restrict__ A,
    const unsigned short* __restrict__ Bpk,
    const float* __restrict__ bx,
    const float* __restrict__ c_child,
    unsigned short* __restrict__ h_out,
    float* __restrict__ c_out,
    float* __restrict__ h_f32_out,
    int n) {
  constexpr int K = KT * 32;
  const int lane = threadIdx.x & 63;
  const int wid = threadIdx.x >> 6;
  const int wm = wid & 1, wn = wid >> 1;
  const int row0 = blockIdx.x * 64 + wm * 32;  // wave's first output row
  const int j0 = blockIdx.y * 64 + wn * 32;    // wave's first h-col

  f32x4 acc[2][2][5];
#pragma unroll
  for (int m = 0; m < 2; ++m)
#pragma unroll
    for (int nn = 0; nn < 2; ++nn)
#pragma unroll
      for (int g = 0; g < 5; ++g) acc[m][nn][g] = (f32x4)0.0f;

  const int arow = row0 + (lane & 15);
  const int kchunk = (lane >> 4) * 8;

  for (int kt = 0; kt < KT; ++kt) {
    const int k0 = kt * 32;
    bf16x8 a[2];
#pragma unroll
    for (int m = 0; m < 2; ++m)
      a[m] = *(const bf16x8*)(A + (size_t)(arow + m * 16) * K + k0 + kchunk);
#pragma unroll
    for (int g = 0; g < 5; ++g) {
#pragma unroll
      for (int nn = 0; nn < 2; ++nn) {
        const int nf = g * 8 + (j0 >> 4) + nn;
        bf16x8 b = *(const bf16x8*)(Bpk + ((size_t)(nf * KT + kt) * 64 + lane) * 8);
        acc[0][nn][g] = __builtin_amdgcn_mfma_f32_16x16x32_bf16(a[0], b, acc[0][nn][g], 0, 0, 0);
        acc[1][nn][g] = __builtin_amdgcn_mfma_f32_16x16x32_bf16(a[1], b, acc[1][nn][g], 0, 0, 0);
      }
    }
  }

  // Epilogue: C/D frag mapping col = lane&15, row = (lane>>4)*4 + reg.
  const int jc = j0 + (lane & 15);
  float bxv[5][2];
#pragma unroll
  for (int g = 0; g < 5; ++g)
#pragma unroll
    for (int nn = 0; nn < 2; ++nn) bxv[g][nn] = bx[g * 128 + jc + nn * 16];

#pragma unroll
  for (int m = 0; m < 2; ++m) {
    const int rb = row0 + m * 16 + (lane >> 4) * 4;
#pragma unroll
    for (int reg = 0; reg < 4; ++reg) {
      const int i = rb + reg;
      if (i >= n) continue;
#pragma unroll
      for (int nn = 0; nn < 2; ++nn) {
        const int j = jc + nn * 16;
        float gi = acc[m][nn][0][reg] + bxv[0][nn];
        float go = acc[m][nn][3][reg] + bxv[3][nn];
        float gu = acc[m][nn][4][reg] + bxv[4][nn];
        float c = sigf(gi) * tanh_fast(gu);
        if (!LEAF) {
          float gfL = acc[m][nn][1][reg] + bxv[1][nn];
          float gfR = acc[m][nn][2][reg] + bxv[2][nn];
          float cL = c_child[(size_t)(2 * i) * HH + j];
          float cR = c_child[(size_t)(2 * i + 1) * HH + j];
          c += sigf(gfL) * cL + sigf(gfR) * cR;
        }
        float h = sigf(go) * tanh_fast(c);
        h_out[(size_t)i * HH + j] = f2bf(h);
        c_out[(size_t)i * HH + j] = c;
        if (h_f32_out) h_f32_out[(size_t)i * HH + j] = h;
      }
    }
  }
}

// ---------------------------------------------------------------------------
extern "C" void kernel_launch(void* const* d_in, const int* in_sizes, int n_in,
                              void* d_out, int out_size, void* d_ws, size_t ws_size,
                              hipStream_t stream) {
  const float* leaf = (const float*)d_in[0];
  const float* Wx = (const float*)d_in[1];
  const float* bx = (const float*)d_in[2];
  const float* UL = (const float*)d_in[3];
  const float* UR = (const float*)d_in[4];
  float* out = (float*)d_out;

  char* ws = (char*)d_ws;
  size_t off = 0;
  auto alloc = [&](size_t bytes) -> void* {
    void* p = ws + off;
    off += (bytes + 1023) & ~(size_t)1023;
    return p;
  };
  unsigned short* Wx_pk = (unsigned short*)alloc((size_t)40 * 4 * 64 * 8 * 2);
  unsigned short* U_pk = (unsigned short*)alloc((size_t)40 * 8 * 64 * 8 * 2);
  unsigned short* leaf_bf = (unsigned short*)alloc((size_t)NLEAF * HH * 2);
  unsigned short* hA = (unsigned short*)alloc((size_t)NLEAF * HH * 2);
  unsigned short* hB = (unsigned short*)alloc((size_t)(NLEAF / 2) * HH * 2);
  float* cA = (float*)alloc((size_t)NLEAF * HH * 4);
  float* cB = (float*)alloc((size_t)(NLEAF / 2) * HH * 4);
  // total ws use ~370 MB

  pack_weights<<<(40 * 4 * 64 + 255) / 256, 256, 0, stream>>>(Wx, Wx, 128, 4, Wx_pk);
  pack_weights<<<(40 * 8 * 64 + 255) / 256, 256, 0, stream>>>(UL, UR, 128, 8, U_pk);
  long n8 = (long)NLEAF * HH / 8;
  cast_leaf<<<(unsigned)(n8 / 256), 256, 0, stream>>>(leaf, leaf_bf, n8);

  // Leaf level: [262144,128] @ Wx[128,640]
  level_fused<4, true><<<dim3(NLEAF / 64, 2), 256, 0, stream>>>(
      leaf_bf, Wx_pk, bx, nullptr, hA, cA, nullptr, NLEAF);

  unsigned short* hs[2] = {hA, hB};
  float* cs[2] = {cA, cB};
  int cur = 0;
  int n = NLEAF / 2;
  for (int lvl = 1; lvl <= 18; ++lvl) {
    unsigned short* hin = hs[cur];
    float* cin = cs[cur];
    unsigned short* hout = hs[cur ^ 1];
    float* cout = cs[cur ^ 1];
    float* f32out = (lvl == 18) ? out : nullptr;
    int gx = (n + 63) / 64;
    level_fused<8, false><<<dim3(gx, 2), 256, 0, stream>>>(
        hin, U_pk, bx, cin, hout, cout, f32out, n);
    cur ^= 1;
    n >>= 1;
  }
  (void)in_sizes; (void)n_in; (void)out_size; (void)ws_size;
}

// Round 4
// 761.383 us; speedup vs baseline: 1.1335x; 1.1335x over previous
//
#include <hip/hip_runtime.h>
#include <hip/hip_bf16.h>
#include <stdint.h>

// TreeLSTM on MI355X. H=D=128, 5H=640, N_LEAVES=2^18, 18 internal levels.
// v2: LDS-resident weight panel per block (staged once, no barriers in main
// loop), grid-stride row loop, fused leaf f32->bf16 conversion.
// Block = 512 thr (8 waves), owns 16 h-cols (= 5 gate cols x 16) x 256 rows/tile.

#define H5 640
#define HH 128
#define NLEAF 262144

typedef __attribute__((ext_vector_type(4))) float f32x4;
typedef __attribute__((ext_vector_type(8))) short bf16x8;
typedef __attribute__((ext_vector_type(4))) unsigned int u32x4;

static __device__ __forceinline__ unsigned int f2bf(float f) {
  union { float f; unsigned int i; } v; v.f = f;
  unsigned int r = v.i + 0x7FFF + ((v.i >> 16) & 1);  // RNE
  return r >> 16;
}

static __device__ __forceinline__ float sigf(float x) {
  return 1.0f / (1.0f + __expf(-x));
}
static __device__ __forceinline__ float tanh_fast(float x) {
  float t = __expf(2.0f * x);
  return (t - 1.0f) / (t + 1.0f);
}

// ---------------------------------------------------------------------------
// Pack a [K,640] f32 weight (rows k<split from srcA, else srcB) into MFMA
// B-fragment layout: frag (nf,kf): lane l holds B[kf*32+(l>>4)*8+e][nf*16+(l&15)],
// e=0..7. Element offset = ((nf*KT + kf)*64 + lane)*8.  (validated round 1)
__global__ void pack_weights(const float* __restrict__ srcA,
                             const float* __restrict__ srcB,
                             int split, int KT, unsigned short* __restrict__ dst) {
  int t = blockIdx.x * blockDim.x + threadIdx.x;
  int total = 40 * KT * 64;
  if (t >= total) return;
  int lane = t & 63;
  int kf = (t >> 6) % KT;
  int nf = (t >> 6) / KT;
  int col = nf * 16 + (lane & 15);
  int k0 = kf * 32 + (lane >> 4) * 8;
  unsigned int w[4];
#pragma unroll
  for (int p = 0; p < 4; ++p) {
    int ka = k0 + 2 * p, kb = k0 + 2 * p + 1;
    float fa = (ka < split) ? srcA[(size_t)ka * H5 + col] : srcB[(size_t)(ka - split) * H5 + col];
    float fb = (kb < split) ? srcA[(size_t)kb * H5 + col] : srcB[(size_t)(kb - split) * H5 + col];
    w[p] = f2bf(fa) | (f2bf(fb) << 16);
  }
  u32x4 v; unsigned int* vp = (unsigned int*)&v;
  vp[0] = w[0]; vp[1] = w[1]; vp[2] = w[2]; vp[3] = w[3];
  *((u32x4*)(dst + (size_t)t * 8)) = v;
}

// ---------------------------------------------------------------------------
// Fused level kernel.
//   A: [n][K] row-major; f32 at leaf (converted in-reg), bf16 internal.
//   Block: 8 waves. by = blockIdx.y in 0..7 selects 16 h-cols (nf = g*8+by).
//   B panel (5*KT frags, 1KB each) staged to LDS once; grid-stride row loop.
template <int KT, bool LEAF>
__global__ __launch_bounds__(512, 4) void level_fused(
    const void* __restrict__ Araw,
    const unsigned short* __restrict__ Bpk,
    const float* __restrict__ bx,
    const float* __restrict__ c_child,
    unsigned short* __restrict__ h_out,
    float* __restrict__ c_out,
    float* __restrict__ h_f32_out,
    int n, int NT) {
  constexpr int K = KT * 32;
  __shared__ unsigned short smemB[5 * KT * 512];  // 5*KT KB (20KB leaf / 40KB int)
  const int lane = threadIdx.x & 63;
  const int wid = threadIdx.x >> 6;
  const int by = blockIdx.y;

  // ---- stage B panel once: LDS frag e=(g*KT+kt) <- global frag ((g*8+by)*KT+kt)
  {
    const int F = 5 * KT;
    for (int e = wid; e < F; e += 8) {
      int g = e / KT, kt = e % KT;
      const u32x4* src =
          (const u32x4*)(Bpk + ((size_t)((g * 8 + by) * KT + kt) * 512) + lane * 8);
      *((u32x4*)(smemB + e * 512 + lane * 8)) = *src;
    }
  }
  __syncthreads();

  const int jc = by * 16 + (lane & 15);
  float bxv[5];
#pragma unroll
  for (int g = 0; g < 5; ++g) bxv[g] = bx[g * 128 + jc];

  const unsigned short* Abf = (const unsigned short*)Araw;
  const float* Af = (const float*)Araw;
  const int kch = (lane >> 4) * 8;

  for (int t = blockIdx.x; t < NT; t += gridDim.x) {
    const int r0 = t * 256 + wid * 32 + (lane & 15);
    f32x4 acc[2][5];
#pragma unroll
    for (int m = 0; m < 2; ++m)
#pragma unroll
      for (int g = 0; g < 5; ++g) acc[m][g] = (f32x4)0.0f;

#pragma unroll 2
    for (int kt = 0; kt < KT; ++kt) {
      bf16x8 a[2];
      if (LEAF) {
#pragma unroll
        for (int m = 0; m < 2; ++m) {
          const float* p = Af + (size_t)(r0 + m * 16) * K + kt * 32 + kch;
          float4 x = *(const float4*)p;
          float4 y = *(const float4*)(p + 4);
          union { bf16x8 v; unsigned int u[4]; } w;
          w.u[0] = f2bf(x.x) | (f2bf(x.y) << 16);
          w.u[1] = f2bf(x.z) | (f2bf(x.w) << 16);
          w.u[2] = f2bf(y.x) | (f2bf(y.y) << 16);
          w.u[3] = f2bf(y.z) | (f2bf(y.w) << 16);
          a[m] = w.v;
        }
      } else {
#pragma unroll
        for (int m = 0; m < 2; ++m)
          a[m] = *(const bf16x8*)(Abf + (size_t)(r0 + m * 16) * K + kt * 32 + kch);
      }
#pragma unroll
      for (int g = 0; g < 5; ++g) {
        bf16x8 b = *(const bf16x8*)(smemB + (g * KT + kt) * 512 + lane * 8);
        acc[0][g] = __builtin_amdgcn_mfma_f32_16x16x32_bf16(a[0], b, acc[0][g], 0, 0, 0);
        acc[1][g] = __builtin_amdgcn_mfma_f32_16x16x32_bf16(a[1], b, acc[1][g], 0, 0, 0);
      }
    }

    // Epilogue. C/D frag: col = lane&15 (=jc), row = (lane>>4)*4 + reg.
#pragma unroll
    for (int m = 0; m < 2; ++m) {
      const int ib = t * 256 + wid * 32 + m * 16 + (lane >> 4) * 4;
#pragma unroll
      for (int reg = 0; reg < 4; ++reg) {
        const int i = ib + reg;
        if (i >= n) continue;
        float gi = acc[m][0][reg] + bxv[0];
        float go = acc[m][3][reg] + bxv[3];
        float gu = acc[m][4][reg] + bxv[4];
        float c = sigf(gi) * tanh_fast(gu);
        if (!LEAF) {
          float gfL = acc[m][1][reg] + bxv[1];
          float gfR = acc[m][2][reg] + bxv[2];
          float cL = c_child[(size_t)(2 * i) * HH + jc];
          float cR = c_child[(size_t)(2 * i + 1) * HH + jc];
          c += sigf(gfL) * cL + sigf(gfR) * cR;
        }
        float h = sigf(go) * tanh_fast(c);
        h_out[(size_t)i * HH + jc] = (unsigned short)f2bf(h);
        c_out[(size_t)i * HH + jc] = c;
        if (h_f32_out) h_f32_out[(size_t)i * HH + jc] = h;
      }
    }
  }
}

// ---------------------------------------------------------------------------
extern "C" void kernel_launch(void* const* d_in, const int* in_sizes, int n_in,
                              void* d_out, int out_size, void* d_ws, size_t ws_size,
                              hipStream_t stream) {
  const float* leaf = (const float*)d_in[0];
  const float* Wx = (const float*)d_in[1];
  const float* bx = (const float*)d_in[2];
  const float* UL = (const float*)d_in[3];
  const float* UR = (const float*)d_in[4];
  float* out = (float*)d_out;

  char* ws = (char*)d_ws;
  size_t off = 0;
  auto alloc = [&](size_t bytes) -> void* {
    void* p = ws + off;
    off += (bytes + 1023) & ~(size_t)1023;
    return p;
  };
  unsigned short* Wx_pk = (unsigned short*)alloc((size_t)40 * 4 * 64 * 8 * 2);
  unsigned short* U_pk = (unsigned short*)alloc((size_t)40 * 8 * 64 * 8 * 2);
  unsigned short* hA = (unsigned short*)alloc((size_t)NLEAF * HH * 2);
  unsigned short* hB = (unsigned short*)alloc((size_t)(NLEAF / 2) * HH * 2);
  float* cA = (float*)alloc((size_t)NLEAF * HH * 4);
  float* cB = (float*)alloc((size_t)(NLEAF / 2) * HH * 4);

  pack_weights<<<(40 * 4 * 64 + 255) / 256, 256, 0, stream>>>(Wx, Wx, 128, 4, Wx_pk);
  pack_weights<<<(40 * 8 * 64 + 255) / 256, 256, 0, stream>>>(UL, UR, 128, 8, U_pk);

  // Leaf: [262144,128] f32 @ Wx[128,640], cast fused. NT=1024 row tiles.
  {
    int NT = NLEAF / 256;  // 1024
    int gx = 128;          // 1024 blocks total (4/CU), 8 tiles each
    level_fused<4, true><<<dim3(gx, 8), 512, 0, stream>>>(
        leaf, Wx_pk, bx, nullptr, hA, cA, nullptr, NLEAF, NT);
  }

  unsigned short* hs[2] = {hA, hB};
  float* cs[2] = {cA, cB};
  int cur = 0;
  int n = NLEAF / 2;
  for (int lvl = 1; lvl <= 18; ++lvl) {
    unsigned short* hin = hs[cur];
    float* cin = cs[cur];
    unsigned short* hout = hs[cur ^ 1];
    float* cout = cs[cur ^ 1];
    float* f32out = (lvl == 18) ? out : nullptr;
    int NT = (n + 255) / 256;
    int gx = NT < 96 ? NT : 96;  // 768 blocks max (3/CU)
    level_fused<8, false><<<dim3(gx, 8), 512, 0, stream>>>(
        hin, U_pk, bx, cin, hout, cout, f32out, n, NT);
    cur ^= 1;
    n >>= 1;
  }
  (void)in_sizes; (void)n_in; (void)out_size; (void)ws_size;
}